// Round 1
// baseline (11836.961 us; speedup 1.0000x reference)
//
#include <hip/hip_runtime.h>

#define Bsz 512
#define Tsz 128
#define Esz 256
#define Hsz 512
#define Zsz 256

__device__ __forceinline__ float sigm(float x) { return 1.0f / (1.0f + __expf(-x)); }

// ---------------------------------------------------------------------------
// prep: Wsum = dec_W_ih + dec_W_hh; fold biases; init h0,c0 = 0.1
// dec_bias0 = dec_b_ih + dec_b_hh + 0.1*rowsum(dec_W_ih)   (decoder step 0)
// ---------------------------------------------------------------------------
__global__ __launch_bounds__(256) void prep_kernel(
    const float* __restrict__ enc_b_ih, const float* __restrict__ enc_b_hh,
    const float* __restrict__ dec_b_ih, const float* __restrict__ dec_b_hh,
    const float* __restrict__ dec_W_ih, const float* __restrict__ dec_W_hh,
    float* __restrict__ Wsum, float* __restrict__ enc_bias,
    float* __restrict__ dec_bias, float* __restrict__ dec_bias0,
    float* __restrict__ h0, float* __restrict__ c0)
{
    const int tid = blockIdx.x * 256 + threadIdx.x;   // grid: 512 blocks -> 131072 threads
    const int NT  = 512 * 256;
    for (int i = tid; i < Bsz * Hsz; i += NT) { h0[i] = 0.1f; c0[i] = 0.1f; }
    for (int i = tid; i < 4 * Hsz * Hsz; i += NT) Wsum[i] = dec_W_ih[i] + dec_W_hh[i];

    // one wave per gate-row (2048 waves exactly)
    const int wave = tid >> 6, lane = tid & 63;
    float s = 0.f;
    for (int k = lane; k < Hsz; k += 64) s += dec_W_ih[wave * Hsz + k];
    for (int off = 32; off; off >>= 1) s += __shfl_down(s, off);
    if (lane == 0) {
        float bi = dec_b_ih[wave] + dec_b_hh[wave];
        dec_bias[wave]  = bi;
        dec_bias0[wave] = bi + 0.1f * s;
        enc_bias[wave]  = enc_b_ih[wave] + enc_b_hh[wave];
    }
}

// ---------------------------------------------------------------------------
// One LSTM step: gates = [Ax | hprev] @ [Wx | Wh]^T + bias, then elementwise.
// Block: 64 batch rows x 16 j-columns (x4 gates = 64 gemm cols). 256 threads.
// Grid: (512/64=8, 512/16=32) = 256 blocks.
// ---------------------------------------------------------------------------
template <bool HAS_X>
__global__ __launch_bounds__(256) void lstm_step(
    const float* __restrict__ Ax, int strideAx,          // [B,*] x_t slice (HAS_X)
    const float* __restrict__ Wx,                        // [4H,E] (HAS_X)
    const float* __restrict__ hprev,                     // [B,H]
    const float* __restrict__ Wh,                        // [4H,H]
    const float* __restrict__ bias,                      // [4H]
    float* __restrict__ c, float* __restrict__ hout)     // [B,H]
{
    __shared__ float AlT[16][64];     // [k][m]
    __shared__ float WlT[16][64];     // [k][n], n = gate*16 + jj
    __shared__ float gbuf[64][65];    // [n][m] gate exchange

    const int tid = threadIdx.x;
    const int tx = tid & 15, ty = tid >> 4;
    const int b0 = blockIdx.x * 64;
    const int j0 = blockIdx.y * 16;
    const int m0 = ty * 4, n0 = tx * 4;

    float acc[4][4];
#pragma unroll
    for (int j = 0; j < 4; ++j) {
        const int n = n0 + j;
        const float bv = bias[(n >> 4) * Hsz + j0 + (n & 15)];
#pragma unroll
        for (int i = 0; i < 4; ++i) acc[i][j] = bv;
    }

    const int lm = tid >> 2;          // 0..63 : A-row / gemm-col
    const int lk = (tid & 3) * 4;     // 0,4,8,12
    const int wrow = (lm >> 4) * Hsz + j0 + (lm & 15);   // W matrix row for col lm

    auto run_phase = [&](const float* Ap, int As, const float* Wp, int Ws, int K) {
        for (int k0 = 0; k0 < K; k0 += 16) {
            const float4 av = *(const float4*)(Ap + (b0 + lm) * As + k0 + lk);
            const float4 wv = *(const float4*)(Wp + wrow * Ws + k0 + lk);
            __syncthreads();
            AlT[lk + 0][lm] = av.x; AlT[lk + 1][lm] = av.y;
            AlT[lk + 2][lm] = av.z; AlT[lk + 3][lm] = av.w;
            WlT[lk + 0][lm] = wv.x; WlT[lk + 1][lm] = wv.y;
            WlT[lk + 2][lm] = wv.z; WlT[lk + 3][lm] = wv.w;
            __syncthreads();
#pragma unroll
            for (int kk = 0; kk < 16; ++kk) {
                const float4 a = *(const float4*)&AlT[kk][m0];
                const float4 w = *(const float4*)&WlT[kk][n0];
                const float aa[4] = {a.x, a.y, a.z, a.w};
                const float ww[4] = {w.x, w.y, w.z, w.w};
#pragma unroll
                for (int i = 0; i < 4; ++i)
#pragma unroll
                    for (int j = 0; j < 4; ++j) acc[i][j] += aa[i] * ww[j];
            }
        }
    };

    if (HAS_X) run_phase(Ax, strideAx, Wx, Esz, Esz);
    run_phase(hprev, Hsz, Wh, Hsz, Hsz);

    __syncthreads();
#pragma unroll
    for (int j = 0; j < 4; ++j)
#pragma unroll
        for (int i = 0; i < 4; ++i) gbuf[n0 + j][m0 + i] = acc[i][j];
    __syncthreads();

#pragma unroll
    for (int r = 0; r < 4; ++r) {
        const int q = r * 256 + tid;
        const int m = q >> 4, jj = q & 15;
        const float ig = gbuf[jj][m];
        const float fg = gbuf[16 + jj][m];
        const float gg = gbuf[32 + jj][m];
        const float og = gbuf[48 + jj][m];
        const float iv = sigm(ig), fv = sigm(fg);
        const float gv = tanhf(gg), ov = sigm(og);
        const int idx = (b0 + m) * Hsz + j0 + jj;
        const float cn = fv * c[idx] + iv * gv;
        c[idx]    = cn;
        hout[idx] = ov * tanhf(cn);
    }
}

// ---------------------------------------------------------------------------
// z-projection: out[:, t, :] = tanh(h @ z_W^T + z_b)
// Block: 64 rows x 16 cols, 256 threads. Grid (8, 16) = 128 blocks.
// ---------------------------------------------------------------------------
__global__ __launch_bounds__(256) void z_proj(
    const float* __restrict__ h, const float* __restrict__ zW,
    const float* __restrict__ zb, float* __restrict__ out, int t)
{
    __shared__ float AlT[16][64];
    __shared__ float WlT[16][16];

    const int tid = threadIdx.x;
    const int tx = tid & 15, ty = tid >> 4;
    const int b0 = blockIdx.x * 64;
    const int n0 = blockIdx.y * 16;
    const int m0 = ty * 4;

    float acc[4];
    {
        const float bv = zb[n0 + tx];
#pragma unroll
        for (int i = 0; i < 4; ++i) acc[i] = bv;
    }

    const int lm = tid >> 2, lk = (tid & 3) * 4;

    for (int k0 = 0; k0 < Hsz; k0 += 16) {
        const float4 av = *(const float4*)(h + (b0 + lm) * Hsz + k0 + lk);
        float4 wv = {0, 0, 0, 0};
        if (tid < 64) wv = *(const float4*)(zW + (n0 + lm) * Hsz + k0 + lk);
        __syncthreads();
        AlT[lk + 0][lm] = av.x; AlT[lk + 1][lm] = av.y;
        AlT[lk + 2][lm] = av.z; AlT[lk + 3][lm] = av.w;
        if (tid < 64) {
            WlT[lk + 0][lm] = wv.x; WlT[lk + 1][lm] = wv.y;
            WlT[lk + 2][lm] = wv.z; WlT[lk + 3][lm] = wv.w;
        }
        __syncthreads();
#pragma unroll
        for (int kk = 0; kk < 16; ++kk) {
            const float4 a = *(const float4*)&AlT[kk][m0];
            const float w = WlT[kk][tx];
            acc[0] += a.x * w; acc[1] += a.y * w;
            acc[2] += a.z * w; acc[3] += a.w * w;
        }
        __syncthreads();
    }

#pragma unroll
    for (int i = 0; i < 4; ++i)
        out[(b0 + m0 + i) * (Tsz * Zsz) + t * Zsz + n0 + tx] = tanhf(acc[i]);
}

// ---------------------------------------------------------------------------
extern "C" void kernel_launch(void* const* d_in, const int* in_sizes, int n_in,
                              void* d_out, int out_size, void* d_ws, size_t ws_size,
                              hipStream_t stream) {
    const float* x        = (const float*)d_in[0];
    const float* enc_W_ih = (const float*)d_in[1];
    const float* enc_W_hh = (const float*)d_in[2];
    const float* enc_b_ih = (const float*)d_in[3];
    const float* enc_b_hh = (const float*)d_in[4];
    const float* dec_W_ih = (const float*)d_in[5];
    const float* dec_W_hh = (const float*)d_in[6];
    const float* dec_b_ih = (const float*)d_in[7];
    const float* dec_b_hh = (const float*)d_in[8];
    const float* z_W      = (const float*)d_in[9];
    const float* z_b      = (const float*)d_in[10];
    float* out = (float*)d_out;

    float* ws = (float*)d_ws;
    float* hA        = ws;                         // [B,H]
    float* hB        = hA + Bsz * Hsz;             // [B,H]
    float* cbuf      = hB + Bsz * Hsz;             // [B,H]
    float* Wsum      = cbuf + Bsz * Hsz;           // [4H,H]
    float* enc_bias  = Wsum + 4 * Hsz * Hsz;       // [4H]
    float* dec_bias  = enc_bias + 4 * Hsz;         // [4H]
    float* dec_bias0 = dec_bias + 4 * Hsz;         // [4H]

    prep_kernel<<<512, 256, 0, stream>>>(enc_b_ih, enc_b_hh, dec_b_ih, dec_b_hh,
                                         dec_W_ih, dec_W_hh, Wsum, enc_bias,
                                         dec_bias, dec_bias0, hA, cbuf);

    const dim3 sgrid(Bsz / 64, Hsz / 16);   // 8 x 32 = 256 blocks
    const dim3 zgrid(Bsz / 64, Zsz / 16);   // 8 x 16 = 128 blocks

    // encoder: h0 in hA; step t reads hbuf[t&1] writes hbuf[(t+1)&1]
    for (int t = 0; t < Tsz; ++t) {
        const float* hp = (t & 1) ? hB : hA;
        float*       ho = (t & 1) ? hA : hB;
        lstm_step<true><<<sgrid, 256, 0, stream>>>(x + t * Esz, Tsz * Esz, enc_W_ih,
                                                   hp, enc_W_hh, enc_bias, cbuf, ho);
    }
    // hx now in hA (t=127 wrote hA); cx in cbuf

    for (int t = 0; t < Tsz; ++t) {
        const float* hp = (t & 1) ? hB : hA;
        float*       ho = (t & 1) ? hA : hB;
        if (t == 0)
            lstm_step<false><<<sgrid, 256, 0, stream>>>(nullptr, 0, nullptr,
                                                        hp, dec_W_hh, dec_bias0, cbuf, ho);
        else
            lstm_step<false><<<sgrid, 256, 0, stream>>>(nullptr, 0, nullptr,
                                                        hp, Wsum, dec_bias, cbuf, ho);
        z_proj<<<zgrid, 256, 0, stream>>>(ho, z_W, z_b, out, t);
    }
}

// Round 2
// 5651.801 us; speedup vs baseline: 2.0944x; 2.0944x over previous
//
#include <hip/hip_runtime.h>

#define Bsz 512
#define Tsz 128
#define Esz 256
#define Hsz 512
#define Zsz 256
#define NG  2048   // 4*Hsz gate columns

typedef unsigned short u16;
typedef __attribute__((ext_vector_type(8))) short short8;
typedef __attribute__((ext_vector_type(4))) float f32x4;

__device__ __forceinline__ float sigm(float x) { return 1.0f / (1.0f + __expf(-x)); }

// fp32 -> bf16 (RNE) and back
__device__ __forceinline__ u16 f2bf(float x) {
    unsigned u = __float_as_uint(x);
    unsigned r = (u + 0x7FFFu + ((u >> 16) & 1u)) >> 16;
    return (u16)r;
}
__device__ __forceinline__ float bf2f(u16 h) { return __uint_as_float(((unsigned)h) << 16); }

// ---------------------------------------------------------------------------
// prep: one-time (per launch) weight conversion to gate-interleaved bf16 hi/lo,
// bias folding, h0/c0 init.  Interleave: B'[n][k] = W[(n&3)*H + (n>>2)][k]
// so a 64-wide n-tile = 16 j's x 4 gates (i,f,g,o adjacent).
// ---------------------------------------------------------------------------
__global__ __launch_bounds__(256) void prep_kernel(
    const float* __restrict__ enc_W_ih, const float* __restrict__ enc_W_hh,
    const float* __restrict__ enc_b_ih, const float* __restrict__ enc_b_hh,
    const float* __restrict__ dec_W_ih, const float* __restrict__ dec_W_hh,
    const float* __restrict__ dec_b_ih, const float* __restrict__ dec_b_hh,
    const float* __restrict__ z_W,
    u16* __restrict__ eih_h, u16* __restrict__ eih_l,
    u16* __restrict__ ehh_h, u16* __restrict__ ehh_l,
    u16* __restrict__ dhh_h, u16* __restrict__ dhh_l,
    u16* __restrict__ wsm_h, u16* __restrict__ wsm_l,
    u16* __restrict__ zw_h,  u16* __restrict__ zw_l,
    float* __restrict__ encB, float* __restrict__ decB, float* __restrict__ decB0,
    float* __restrict__ h0, float* __restrict__ c0)
{
    const int tid = blockIdx.x * 256 + threadIdx.x;   // 512 blocks -> 131072 threads
    const int NT  = 512 * 256;

    for (int i = tid; i < Bsz * Hsz; i += NT) { h0[i] = 0.1f; c0[i] = 0.1f; }

    // enc W_ih: [NG][E]
    for (int i = tid; i < NG * Esz; i += NT) {
        int n = i >> 8, k = i & 255;
        int sr = (n & 3) * Hsz + (n >> 2);
        float v = enc_W_ih[sr * Esz + k];
        u16 h = f2bf(v); eih_h[i] = h; eih_l[i] = f2bf(v - bf2f(h));
    }
    // enc W_hh, dec W_hh, Wsum: [NG][H]
    for (int i = tid; i < NG * Hsz; i += NT) {
        int n = i >> 9, k = i & 511;
        int sr = (n & 3) * Hsz + (n >> 2);
        float v1 = enc_W_hh[sr * Hsz + k];
        u16 h1 = f2bf(v1); ehh_h[i] = h1; ehh_l[i] = f2bf(v1 - bf2f(h1));
        float v2 = dec_W_hh[sr * Hsz + k];
        u16 h2 = f2bf(v2); dhh_h[i] = h2; dhh_l[i] = f2bf(v2 - bf2f(h2));
        float v3 = dec_W_ih[sr * Hsz + k] + v2;
        u16 h3 = f2bf(v3); wsm_h[i] = h3; wsm_l[i] = f2bf(v3 - bf2f(h3));
    }
    // z_W: [Z][H], no interleave
    for (int i = tid; i < Zsz * Hsz; i += NT) {
        float v = z_W[i];
        u16 h = f2bf(v); zw_h[i] = h; zw_l[i] = f2bf(v - bf2f(h));
    }

    // biases (interleaved) + decoder step-0 bias (0.1 * rowsum(dec_W_ih) folded)
    const int wave = tid >> 6, lane = tid & 63;   // exactly 2048 waves
    if (wave < NG) {
        const int sr = (wave & 3) * Hsz + (wave >> 2);
        float s = 0.f;
        for (int k = lane; k < Hsz; k += 64) s += dec_W_ih[sr * Hsz + k];
        for (int off = 32; off; off >>= 1) s += __shfl_down(s, off);
        if (lane == 0) {
            encB[wave] = enc_b_ih[sr] + enc_b_hh[sr];
            float bi = dec_b_ih[sr] + dec_b_hh[sr];
            decB[wave]  = bi;
            decB0[wave] = bi + 0.1f * s;
        }
    }
}

// ---------------------------------------------------------------------------
// LSTM step via bf16 hi/lo split MFMA.
// Block: 64(batch) x 64(gate-col) tile, 256 thr = 4 waves of 32x32 (2x2 frags).
// Grid: (512/64, 2048/64) = (8, 32) = 256 blocks.
// ---------------------------------------------------------------------------
template <bool HAS_X>
__global__ __launch_bounds__(256) void lstm_step(
    const float* __restrict__ Ax, long sAx,               // x_t slice (HAS_X)
    const u16* __restrict__ BXh, const u16* __restrict__ BXl,  // [NG][E]
    const float* __restrict__ hprev,                      // [B,H] fp32
    const u16* __restrict__ BHh, const u16* __restrict__ BHl,  // [NG][H]
    const float* __restrict__ biasI,                      // [NG] interleaved
    float* __restrict__ c, float* __restrict__ hout)
{
    __shared__ u16 As_h[64][40], As_l[64][40];   // 80 B rows -> 2-way max aliasing
    __shared__ u16 Bs_h[64][40], Bs_l[64][40];
    __shared__ float gbuf[64][65];

    const int tid = threadIdx.x;
    const int b0 = blockIdx.x * 64;
    const int n0 = blockIdx.y * 64;
    const int w = tid >> 6, lane = tid & 63;
    const int wm = (w & 1) * 32, wn = (w >> 1) * 32;
    const int lr = lane & 15, lkb = lane >> 4;

    f32x4 acc[2][2];
#pragma unroll
    for (int j = 0; j < 2; ++j) {
        const float bv = biasI[n0 + wn + j * 16 + lr];
        acc[0][j] = (f32x4){bv, bv, bv, bv};
        acc[1][j] = acc[0][j];
    }

    const int srow = tid >> 2;        // 0..63 staging row
    const int sc8  = (tid & 3) * 8;   // 0,8,16,24 (k offset, 8 elems = 16 B)

    const int KT = (HAS_X ? (Esz + Hsz) : Hsz) / 32;

    auto addrs = [&](int kt, const float*& ap, const u16*& bhp, const u16*& blp) {
        if (HAS_X && kt * 32 < Esz) {
            const int k0 = kt * 32;
            ap  = Ax + (long)(b0 + srow) * sAx + k0 + sc8;
            bhp = BXh + (n0 + srow) * Esz + k0 + sc8;
            blp = BXl + (n0 + srow) * Esz + k0 + sc8;
        } else {
            const int k0 = kt * 32 - (HAS_X ? Esz : 0);
            ap  = hprev + (long)(b0 + srow) * Hsz + k0 + sc8;
            bhp = BHh + (n0 + srow) * Hsz + k0 + sc8;
            blp = BHl + (n0 + srow) * Hsz + k0 + sc8;
        }
    };

    const float* ap; const u16* bhp; const u16* blp;
    addrs(0, ap, bhp, blp);
    float4 a0 = *(const float4*)ap, a1 = *(const float4*)(ap + 4);
    short8 bh = *(const short8*)bhp, bl = *(const short8*)blp;

    for (int kt = 0; kt < KT; ++kt) {
        __syncthreads();   // prior tile's frag reads done
        // convert A to hi/lo and stage everything
        {
            const float av[8] = {a0.x, a0.y, a0.z, a0.w, a1.x, a1.y, a1.z, a1.w};
            short8 h8, l8;
#pragma unroll
            for (int r = 0; r < 8; ++r) {
                u16 hh = f2bf(av[r]);
                h8[r] = (short)hh;
                l8[r] = (short)f2bf(av[r] - bf2f(hh));
            }
            *(short8*)&As_h[srow][sc8] = h8;
            *(short8*)&As_l[srow][sc8] = l8;
            *(short8*)&Bs_h[srow][sc8] = bh;
            *(short8*)&Bs_l[srow][sc8] = bl;
        }
        // prefetch next tile (latency hidden under barrier + frag reads + MFMA)
        if (kt + 1 < KT) {
            addrs(kt + 1, ap, bhp, blp);
            a0 = *(const float4*)ap; a1 = *(const float4*)(ap + 4);
            bh = *(const short8*)bhp; bl = *(const short8*)blp;
        }
        __syncthreads();

        short8 Ah[2], Al[2], Bh2[2], Bl2[2];
#pragma unroll
        for (int i = 0; i < 2; ++i) {
            Ah[i]  = *(const short8*)&As_h[wm + i * 16 + lr][lkb * 8];
            Al[i]  = *(const short8*)&As_l[wm + i * 16 + lr][lkb * 8];
            Bh2[i] = *(const short8*)&Bs_h[wn + i * 16 + lr][lkb * 8];
            Bl2[i] = *(const short8*)&Bs_l[wn + i * 16 + lr][lkb * 8];
        }
#pragma unroll
        for (int i = 0; i < 2; ++i)
#pragma unroll
            for (int j = 0; j < 2; ++j) {
                acc[i][j] = __builtin_amdgcn_mfma_f32_16x16x32_bf16(Ah[i], Bh2[j], acc[i][j], 0, 0, 0);
                acc[i][j] = __builtin_amdgcn_mfma_f32_16x16x32_bf16(Ah[i], Bl2[j], acc[i][j], 0, 0, 0);
                acc[i][j] = __builtin_amdgcn_mfma_f32_16x16x32_bf16(Al[i], Bh2[j], acc[i][j], 0, 0, 0);
            }
    }

    // gate exchange: gbuf[n_local][m_local]
    __syncthreads();
#pragma unroll
    for (int i = 0; i < 2; ++i)
#pragma unroll
        for (int j = 0; j < 2; ++j)
#pragma unroll
            for (int r = 0; r < 4; ++r)
                gbuf[wn + j * 16 + lr][wm + i * 16 + lkb * 4 + r] = acc[i][j][r];
    __syncthreads();

    // elementwise: n_local = 4*jj + gate
#pragma unroll
    for (int rep = 0; rep < 4; ++rep) {
        const int q = rep * 256 + tid;
        const int m = q >> 4, jj = q & 15;
        const float gi = gbuf[4 * jj + 0][m];
        const float gf = gbuf[4 * jj + 1][m];
        const float gg = gbuf[4 * jj + 2][m];
        const float go = gbuf[4 * jj + 3][m];
        const float iv = sigm(gi), fv = sigm(gf);
        const float gv = tanhf(gg), ov = sigm(go);
        const long idx = (long)(b0 + m) * Hsz + blockIdx.y * 16 + jj;
        const float cn = fv * c[idx] + iv * gv;
        c[idx]    = cn;
        hout[idx] = ov * tanhf(cn);
    }
}

// ---------------------------------------------------------------------------
// z-projection: out[:,t,:] = tanh(h @ zW^T + zb), MFMA path, 64x64 tiles.
// Grid (8, 4) = 32 blocks.
// ---------------------------------------------------------------------------
__global__ __launch_bounds__(256) void z_proj(
    const float* __restrict__ h,
    const u16* __restrict__ Zh, const u16* __restrict__ Zl,  // [Z][H]
    const float* __restrict__ zb, float* __restrict__ out, int t)
{
    __shared__ u16 As_h[64][40], As_l[64][40];
    __shared__ u16 Bs_h[64][40], Bs_l[64][40];

    const int tid = threadIdx.x;
    const int b0 = blockIdx.x * 64;
    const int n0 = blockIdx.y * 64;
    const int w = tid >> 6, lane = tid & 63;
    const int wm = (w & 1) * 32, wn = (w >> 1) * 32;
    const int lr = lane & 15, lkb = lane >> 4;

    f32x4 acc[2][2];
#pragma unroll
    for (int j = 0; j < 2; ++j) {
        const float bv = zb[n0 + wn + j * 16 + lr];
        acc[0][j] = (f32x4){bv, bv, bv, bv};
        acc[1][j] = acc[0][j];
    }

    const int srow = tid >> 2, sc8 = (tid & 3) * 8;

    const float* ap = h + (long)(b0 + srow) * Hsz + sc8;
    const u16* bhp = Zh + (n0 + srow) * Hsz + sc8;
    const u16* blp = Zl + (n0 + srow) * Hsz + sc8;
    float4 a0 = *(const float4*)ap, a1 = *(const float4*)(ap + 4);
    short8 bh = *(const short8*)bhp, bl = *(const short8*)blp;

    for (int kt = 0; kt < Hsz / 32; ++kt) {
        __syncthreads();
        {
            const float av[8] = {a0.x, a0.y, a0.z, a0.w, a1.x, a1.y, a1.z, a1.w};
            short8 h8, l8;
#pragma unroll
            for (int r = 0; r < 8; ++r) {
                u16 hh = f2bf(av[r]);
                h8[r] = (short)hh;
                l8[r] = (short)f2bf(av[r] - bf2f(hh));
            }
            *(short8*)&As_h[srow][sc8] = h8;
            *(short8*)&As_l[srow][sc8] = l8;
            *(short8*)&Bs_h[srow][sc8] = bh;
            *(short8*)&Bs_l[srow][sc8] = bl;
        }
        if (kt + 1 < Hsz / 32) {
            const int k0 = (kt + 1) * 32;
            a0 = *(const float4*)(h + (long)(b0 + srow) * Hsz + k0 + sc8);
            a1 = *(const float4*)(h + (long)(b0 + srow) * Hsz + k0 + sc8 + 4);
            bh = *(const short8*)(Zh + (n0 + srow) * Hsz + k0 + sc8);
            bl = *(const short8*)(Zl + (n0 + srow) * Hsz + k0 + sc8);
        }
        __syncthreads();

        short8 Ah[2], Al[2], Bh2[2], Bl2[2];
#pragma unroll
        for (int i = 0; i < 2; ++i) {
            Ah[i]  = *(const short8*)&As_h[wm + i * 16 + lr][lkb * 8];
            Al[i]  = *(const short8*)&As_l[wm + i * 16 + lr][lkb * 8];
            Bh2[i] = *(const short8*)&Bs_h[wn + i * 16 + lr][lkb * 8];
            Bl2[i] = *(const short8*)&Bs_l[wn + i * 16 + lr][lkb * 8];
        }
#pragma unroll
        for (int i = 0; i < 2; ++i)
#pragma unroll
            for (int j = 0; j < 2; ++j) {
                acc[i][j] = __builtin_amdgcn_mfma_f32_16x16x32_bf16(Ah[i], Bh2[j], acc[i][j], 0, 0, 0);
                acc[i][j] = __builtin_amdgcn_mfma_f32_16x16x32_bf16(Ah[i], Bl2[j], acc[i][j], 0, 0, 0);
                acc[i][j] = __builtin_amdgcn_mfma_f32_16x16x32_bf16(Al[i], Bh2[j], acc[i][j], 0, 0, 0);
            }
    }

#pragma unroll
    for (int i = 0; i < 2; ++i)
#pragma unroll
        for (int j = 0; j < 2; ++j)
#pragma unroll
            for (int r = 0; r < 4; ++r) {
                const int row = b0 + wm + i * 16 + lkb * 4 + r;
                const int col = n0 + wn + j * 16 + lr;
                out[(long)row * (Tsz * Zsz) + (long)t * Zsz + col] = tanhf(acc[i][j][r]);
            }
}

// ---------------------------------------------------------------------------
extern "C" void kernel_launch(void* const* d_in, const int* in_sizes, int n_in,
                              void* d_out, int out_size, void* d_ws, size_t ws_size,
                              hipStream_t stream) {
    const float* x        = (const float*)d_in[0];
    const float* enc_W_ih = (const float*)d_in[1];
    const float* enc_W_hh = (const float*)d_in[2];
    const float* enc_b_ih = (const float*)d_in[3];
    const float* enc_b_hh = (const float*)d_in[4];
    const float* dec_W_ih = (const float*)d_in[5];
    const float* dec_W_hh = (const float*)d_in[6];
    const float* dec_b_ih = (const float*)d_in[7];
    const float* dec_b_hh = (const float*)d_in[8];
    const float* z_W      = (const float*)d_in[9];
    const float* z_b      = (const float*)d_in[10];
    float* out = (float*)d_out;

    // workspace layout
    float* fp = (float*)d_ws;
    float* hA    = fp;  fp += Bsz * Hsz;
    float* hB    = fp;  fp += Bsz * Hsz;
    float* cbuf  = fp;  fp += Bsz * Hsz;
    float* encB  = fp;  fp += NG;
    float* decB  = fp;  fp += NG;
    float* decB0 = fp;  fp += NG;
    u16* up = (u16*)fp;
    u16* eih_h = up; up += NG * Esz;
    u16* eih_l = up; up += NG * Esz;
    u16* ehh_h = up; up += NG * Hsz;
    u16* ehh_l = up; up += NG * Hsz;
    u16* dhh_h = up; up += NG * Hsz;
    u16* dhh_l = up; up += NG * Hsz;
    u16* wsm_h = up; up += NG * Hsz;
    u16* wsm_l = up; up += NG * Hsz;
    u16* zw_h  = up; up += Zsz * Hsz;
    u16* zw_l  = up; up += Zsz * Hsz;

    prep_kernel<<<512, 256, 0, stream>>>(
        enc_W_ih, enc_W_hh, enc_b_ih, enc_b_hh,
        dec_W_ih, dec_W_hh, dec_b_ih, dec_b_hh, z_W,
        eih_h, eih_l, ehh_h, ehh_l, dhh_h, dhh_l, wsm_h, wsm_l, zw_h, zw_l,
        encB, decB, decB0, hA, cbuf);

    const dim3 sgrid(Bsz / 64, NG / 64);    // 8 x 32 = 256 blocks
    const dim3 zgrid(Bsz / 64, Zsz / 64);   // 8 x 4  = 32 blocks

    for (int t = 0; t < Tsz; ++t) {
        const float* hp = (t & 1) ? hB : hA;
        float*       ho = (t & 1) ? hA : hB;
        lstm_step<true><<<sgrid, 256, 0, stream>>>(
            x + (long)t * Esz, (long)Tsz * Esz, eih_h, eih_l,
            hp, ehh_h, ehh_l, encB, cbuf, ho);
    }
    // hx in hA, cx in cbuf
    for (int t = 0; t < Tsz; ++t) {
        const float* hp = (t & 1) ? hB : hA;
        float*       ho = (t & 1) ? hA : hB;
        if (t == 0)
            lstm_step<false><<<sgrid, 256, 0, stream>>>(
                nullptr, 0, nullptr, nullptr, hp, dhh_h, dhh_l, decB0, cbuf, ho);
        else
            lstm_step<false><<<sgrid, 256, 0, stream>>>(
                nullptr, 0, nullptr, nullptr, hp, wsm_h, wsm_l, decB, cbuf, ho);
        z_proj<<<zgrid, 256, 0, stream>>>(ho, zw_h, zw_l, z_b, out, t);
    }
}

// Round 3
// 2122.296 us; speedup vs baseline: 5.5774x; 2.6631x over previous
//
#include <hip/hip_runtime.h>

#define Bsz 512
#define Tsz 128
#define Esz 256
#define Hsz 512
#define Zsz 256
#define NG  2048   // 4*Hsz interleaved gate columns

typedef _Float16 f16;
typedef __attribute__((ext_vector_type(8))) _Float16 f16x8;
typedef __attribute__((ext_vector_type(4))) float f32x4;

__device__ __forceinline__ float sigm(float x) { return 1.0f / (1.0f + __expf(-x)); }

// dst<->src column swizzle within 64-col tiles: kb ^= (row&7)  (involution)
__device__ __forceinline__ int swz(int kd, int r) {
    return (kd & ~56) | ((((kd >> 3) & 7) ^ (r & 7)) << 3);
}

__device__ __forceinline__ void gld16(const void* g, void* l) {
    __builtin_amdgcn_global_load_lds(
        (const __attribute__((address_space(1))) unsigned*)g,
        (__attribute__((address_space(3))) unsigned*)l, 16, 0, 0);
}

// ---------------------------------------------------------------------------
// prep: weights -> fp16, gate-interleaved (n = 4*j + gate) and k-swizzled;
// bias folding; h0/c0/x0 init.
// ---------------------------------------------------------------------------
__global__ __launch_bounds__(256) void prep_kernel(
    const float* __restrict__ x,
    const float* __restrict__ enc_W_ih, const float* __restrict__ enc_W_hh,
    const float* __restrict__ enc_b_ih, const float* __restrict__ enc_b_hh,
    const float* __restrict__ dec_W_ih, const float* __restrict__ dec_W_hh,
    const float* __restrict__ dec_b_ih, const float* __restrict__ dec_b_hh,
    const float* __restrict__ z_W,
    f16* __restrict__ eih_s, f16* __restrict__ ehh_s,
    f16* __restrict__ dhh_s, f16* __restrict__ wsm_s, f16* __restrict__ zw_s,
    float* __restrict__ encB, float* __restrict__ decB, float* __restrict__ decB0,
    f16* __restrict__ hb0, f16* __restrict__ xb0, float* __restrict__ cbuf)
{
    const int tid = blockIdx.x * 256 + threadIdx.x;   // 512 blocks
    const int NT  = 512 * 256;

    for (int i = tid; i < Bsz * Hsz; i += NT) { cbuf[i] = 0.1f; hb0[i] = (f16)0.1f; }

    // x[:,0,:] -> swizzled fp16
    for (int i = tid; i < Bsz * Esz; i += NT) {
        const int b = i >> 8, kd = i & 255;
        xb0[i] = (f16)x[(size_t)b * (Tsz * Esz) + swz(kd, b)];
    }
    // enc W_ih: [NG][E]
    for (int i = tid; i < NG * Esz; i += NT) {
        const int n = i >> 8, kd = i & 255;
        const int sr = (n & 3) * Hsz + (n >> 2);
        eih_s[i] = (f16)enc_W_ih[sr * Esz + swz(kd, n)];
    }
    // enc W_hh, dec W_hh, Wsum: [NG][H]
    for (int i = tid; i < NG * Hsz; i += NT) {
        const int n = i >> 9, kd = i & 511;
        const int sr = (n & 3) * Hsz + (n >> 2);
        const int ks = swz(kd, n);
        ehh_s[i] = (f16)enc_W_hh[sr * Hsz + ks];
        const float dv = dec_W_hh[sr * Hsz + ks];
        dhh_s[i] = (f16)dv;
        wsm_s[i] = (f16)(dec_W_ih[sr * Hsz + ks] + dv);
    }
    // z_W: [Z][H], no gate interleave, still k-swizzled
    for (int i = tid; i < Zsz * Hsz; i += NT) {
        const int n = i >> 9, kd = i & 511;
        zw_s[i] = (f16)z_W[n * Hsz + swz(kd, n)];
    }

    // biases, interleaved; decoder step-0 bias folds 0.1*rowsum(dec_W_ih)
    const int wave = tid >> 6, lane = tid & 63;   // 2048 waves exactly
    if (wave < NG) {
        const int sr = (wave & 3) * Hsz + (wave >> 2);
        float s = 0.f;
        for (int k = lane; k < Hsz; k += 64) s += dec_W_ih[sr * Hsz + k];
        for (int off = 32; off; off >>= 1) s += __shfl_down(s, off);
        if (lane == 0) {
            encB[wave] = enc_b_ih[sr] + enc_b_hh[sr];
            const float bi = dec_b_ih[sr] + dec_b_hh[sr];
            decB[wave]  = bi;
            decB0[wave] = bi + 0.1f * s;
        }
    }
}

// ---------------------------------------------------------------------------
// LSTM step, fp16 MFMA, 64x64 block tile, K-tile 64, 2-phase gld_lds pipeline.
// ENC grid (8,32); DEC grid (8,36): blockIdx.y>=32 -> fused z for step t-1.
// ---------------------------------------------------------------------------
template <bool ENC>
__global__ __launch_bounds__(256, 2) void lstm_step(
    const f16* __restrict__ xcur, const f16* __restrict__ Wx,   // ENC only
    const f16* __restrict__ hprev, const f16* __restrict__ Wh,
    const float* __restrict__ biasI,
    float* __restrict__ c, f16* __restrict__ hout,
    const float* __restrict__ xglob, f16* __restrict__ xnext,   // ENC only
    const f16* __restrict__ zw, const float* __restrict__ zb,   // DEC only
    float* __restrict__ out, int t)
{
    __shared__ f16 As[2][64 * 64];
    __shared__ f16 Bs[2][64 * 64];
    __shared__ float gbuf[64][65];

    const int tid = threadIdx.x;
    const int lane = tid & 63, w = tid >> 6;
    const int lr = lane & 15, lkb = lane >> 4;
    const int wm = (w & 1) * 32, wn = (w >> 1) * 32;
    const int b0 = blockIdx.x * 64;

    const bool ZPATH = (!ENC) && ((int)blockIdx.y >= 32);
    if (ZPATH && t == 0) return;

    const int n0 = ZPATH ? ((int)blockIdx.y - 32) * 64 : (int)blockIdx.y * 64;
    const f16* Wg = ZPATH ? zw : Wh;

    f32x4 acc[2][2];
#pragma unroll
    for (int j = 0; j < 2; ++j) {
        const float bv = ZPATH ? zb[n0 + wn + j * 16 + lr] : biasI[n0 + wn + j * 16 + lr];
        acc[0][j] = (f32x4){bv, bv, bv, bv};
        acc[1][j] = acc[0][j];
    }

    const int KT = ENC ? 12 : 8;

    auto stage = [&](int buf, int kt) {
        const f16* asrc; const f16* bsrc; int K, k0;
        if (ENC && kt < 4) { asrc = xcur; bsrc = Wx; K = Esz; k0 = kt * 64; }
        else { asrc = hprev; bsrc = Wg; K = Hsz; k0 = (kt - (ENC ? 4 : 0)) * 64; }
        const int rl = lane >> 3, kc = (lane & 7) * 8;
#pragma unroll
        for (int s = 0; s < 2; ++s) {
            const int g = w + s * 4;
            const int row = g * 8 + rl;
            gld16(asrc + (size_t)(b0 + row) * K + k0 + kc, &As[buf][g * 512]);
            gld16(bsrc + (size_t)(n0 + row) * K + k0 + kc, &Bs[buf][g * 512]);
        }
    };

    stage(0, 0);
    int cur = 0;
    for (int kt = 0; kt < KT; ++kt) {
        asm volatile("s_waitcnt vmcnt(0)" ::: "memory");
        __syncthreads();
        if (kt + 1 < KT) stage(cur ^ 1, kt + 1);

        f16x8 a[2][2], b[2][2];
#pragma unroll
        for (int i = 0; i < 2; ++i) {
            const int ra = wm + i * 16 + lr;
            const int rb = wn + i * 16 + lr;
#pragma unroll
            for (int ks = 0; ks < 2; ++ks) {
                const int ka = ((ks * 4 + lkb) ^ (ra & 7)) * 8;
                const int kb = ((ks * 4 + lkb) ^ (rb & 7)) * 8;
                a[i][ks] = *(const f16x8*)&As[cur][ra * 64 + ka];
                b[i][ks] = *(const f16x8*)&Bs[cur][rb * 64 + kb];
            }
        }
#pragma unroll
        for (int ks = 0; ks < 2; ++ks)
#pragma unroll
            for (int i = 0; i < 2; ++i)
#pragma unroll
                for (int j = 0; j < 2; ++j)
                    acc[i][j] = __builtin_amdgcn_mfma_f32_16x16x32_f16(
                        a[i][ks], b[j][ks], acc[i][j], 0, 0, 0);
        cur ^= 1;
    }

    if (!ZPATH) {
        const int j0 = (ENC ? (int)blockIdx.y : (int)blockIdx.y) * 16;
        const int ty = tid >> 4, tx = tid & 15;
        // issue c loads early; they fly during gbuf write + barrier
        float cpre[4];
#pragma unroll
        for (int rep = 0; rep < 4; ++rep)
            cpre[rep] = c[(size_t)(b0 + rep * 16 + ty) * Hsz + j0 + tx];
#pragma unroll
        for (int i = 0; i < 2; ++i)
#pragma unroll
            for (int j = 0; j < 2; ++j)
#pragma unroll
                for (int r = 0; r < 4; ++r)
                    gbuf[wn + j * 16 + lr][wm + i * 16 + lkb * 4 + r] = acc[i][j][r];
        __syncthreads();
#pragma unroll
        for (int rep = 0; rep < 4; ++rep) {
            const int m = rep * 16 + ty, jj = tx;
            const float gi = gbuf[4 * jj + 0][m];
            const float gf = gbuf[4 * jj + 1][m];
            const float gg = gbuf[4 * jj + 2][m];
            const float go = gbuf[4 * jj + 3][m];
            const float iv = sigm(gi), fv = sigm(gf);
            const float gv = tanhf(gg), ov = sigm(go);
            const float cn = fv * cpre[rep] + iv * gv;
            const int bq = b0 + m, col = j0 + jj;
            c[(size_t)bq * Hsz + col] = cn;
            hout[(size_t)bq * Hsz + swz(col, bq)] = (f16)(ov * tanhf(cn));
        }
        // convert x[:,t+1,:] for the next encoder step
        if (ENC && t + 1 < Tsz) {
            const int gid = ((int)blockIdx.y * (int)gridDim.x + (int)blockIdx.x) * 256 + tid;
#pragma unroll
            for (int r2 = 0; r2 < 2; ++r2) {
                const int idx = r2 * 65536 + gid;
                const int bq = idx >> 8, kd = idx & 255;
                xnext[(size_t)bq * Esz + kd] =
                    (f16)xglob[(size_t)bq * (Tsz * Esz) + (t + 1) * Esz + swz(kd, bq)];
            }
        }
    } else {
#pragma unroll
        for (int i = 0; i < 2; ++i)
#pragma unroll
            for (int j = 0; j < 2; ++j)
#pragma unroll
                for (int r = 0; r < 4; ++r) {
                    const int row = b0 + wm + i * 16 + lkb * 4 + r;
                    const int col = n0 + wn + j * 16 + lr;
                    out[(size_t)row * (Tsz * Zsz) + (size_t)(t - 1) * Zsz + col] =
                        tanhf(acc[i][j][r]);
                }
    }
}

// ---------------------------------------------------------------------------
// final z projection for t = 127
// ---------------------------------------------------------------------------
__global__ __launch_bounds__(256, 2) void z_final(
    const f16* __restrict__ h, const f16* __restrict__ zw,
    const float* __restrict__ zb, float* __restrict__ out)
{
    __shared__ f16 As[2][64 * 64];
    __shared__ f16 Bs[2][64 * 64];

    const int tid = threadIdx.x;
    const int lane = tid & 63, w = tid >> 6;
    const int lr = lane & 15, lkb = lane >> 4;
    const int wm = (w & 1) * 32, wn = (w >> 1) * 32;
    const int b0 = blockIdx.x * 64;
    const int n0 = blockIdx.y * 64;

    f32x4 acc[2][2];
#pragma unroll
    for (int j = 0; j < 2; ++j) {
        const float bv = zb[n0 + wn + j * 16 + lr];
        acc[0][j] = (f32x4){bv, bv, bv, bv};
        acc[1][j] = acc[0][j];
    }

    auto stage = [&](int buf, int kt) {
        const int rl = lane >> 3, kc = (lane & 7) * 8, k0 = kt * 64;
#pragma unroll
        for (int s = 0; s < 2; ++s) {
            const int g = w + s * 4;
            const int row = g * 8 + rl;
            gld16(h  + (size_t)(b0 + row) * Hsz + k0 + kc, &As[buf][g * 512]);
            gld16(zw + (size_t)(n0 + row) * Hsz + k0 + kc, &Bs[buf][g * 512]);
        }
    };

    stage(0, 0);
    int cur = 0;
    for (int kt = 0; kt < 8; ++kt) {
        asm volatile("s_waitcnt vmcnt(0)" ::: "memory");
        __syncthreads();
        if (kt + 1 < 8) stage(cur ^ 1, kt + 1);
        f16x8 a[2][2], b[2][2];
#pragma unroll
        for (int i = 0; i < 2; ++i) {
            const int ra = wm + i * 16 + lr;
            const int rb = wn + i * 16 + lr;
#pragma unroll
            for (int ks = 0; ks < 2; ++ks) {
                a[i][ks] = *(const f16x8*)&As[cur][ra * 64 + (((ks * 4 + lkb) ^ (ra & 7)) * 8)];
                b[i][ks] = *(const f16x8*)&Bs[cur][rb * 64 + (((ks * 4 + lkb) ^ (rb & 7)) * 8)];
            }
        }
#pragma unroll
        for (int ks = 0; ks < 2; ++ks)
#pragma unroll
            for (int i = 0; i < 2; ++i)
#pragma unroll
                for (int j = 0; j < 2; ++j)
                    acc[i][j] = __builtin_amdgcn_mfma_f32_16x16x32_f16(
                        a[i][ks], b[j][ks], acc[i][j], 0, 0, 0);
        cur ^= 1;
    }
#pragma unroll
    for (int i = 0; i < 2; ++i)
#pragma unroll
        for (int j = 0; j < 2; ++j)
#pragma unroll
            for (int r = 0; r < 4; ++r) {
                const int row = b0 + wm + i * 16 + lkb * 4 + r;
                const int col = n0 + wn + j * 16 + lr;
                out[(size_t)row * (Tsz * Zsz) + (size_t)127 * Zsz + col] = tanhf(acc[i][j][r]);
            }
}

// ---------------------------------------------------------------------------
extern "C" void kernel_launch(void* const* d_in, const int* in_sizes, int n_in,
                              void* d_out, int out_size, void* d_ws, size_t ws_size,
                              hipStream_t stream) {
    const float* x        = (const float*)d_in[0];
    const float* enc_W_ih = (const float*)d_in[1];
    const float* enc_W_hh = (const float*)d_in[2];
    const float* enc_b_ih = (const float*)d_in[3];
    const float* enc_b_hh = (const float*)d_in[4];
    const float* dec_W_ih = (const float*)d_in[5];
    const float* dec_W_hh = (const float*)d_in[6];
    const float* dec_b_ih = (const float*)d_in[7];
    const float* dec_b_hh = (const float*)d_in[8];
    const float* z_W      = (const float*)d_in[9];
    const float* z_b      = (const float*)d_in[10];
    float* out = (float*)d_out;

    float* cbuf  = (float*)d_ws;                 // [B*H]
    float* encB  = cbuf + Bsz * Hsz;             // [NG]
    float* decB  = encB + NG;
    float* decB0 = decB + NG;
    f16* hb0   = (f16*)(decB0 + NG);             // [B*H]
    f16* hb1   = hb0 + Bsz * Hsz;
    f16* xb0   = hb1 + Bsz * Hsz;                // [B*E]
    f16* xb1   = xb0 + Bsz * Esz;
    f16* eih_s = xb1 + Bsz * Esz;                // [NG*E]
    f16* ehh_s = eih_s + NG * Esz;               // [NG*H]
    f16* dhh_s = ehh_s + NG * Hsz;
    f16* wsm_s = dhh_s + NG * Hsz;
    f16* zw_s  = wsm_s + NG * Hsz;               // [Z*H]

    prep_kernel<<<512, 256, 0, stream>>>(
        x, enc_W_ih, enc_W_hh, enc_b_ih, enc_b_hh,
        dec_W_ih, dec_W_hh, dec_b_ih, dec_b_hh, z_W,
        eih_s, ehh_s, dhh_s, wsm_s, zw_s, encB, decB, decB0, hb0, xb0, cbuf);

    f16* hb[2] = {hb0, hb1};
    f16* xb[2] = {xb0, xb1};
    const dim3 egrid(8, 32), dgrid(8, 36), zgrid(8, 4);

    for (int t = 0; t < Tsz; ++t)
        lstm_step<true><<<egrid, 256, 0, stream>>>(
            xb[t & 1], eih_s, hb[t & 1], ehh_s, encB, cbuf, hb[(t + 1) & 1],
            x, xb[(t + 1) & 1], nullptr, nullptr, nullptr, t);

    for (int t = 0; t < Tsz; ++t)
        lstm_step<false><<<dgrid, 256, 0, stream>>>(
            nullptr, nullptr, hb[t & 1], (t == 0) ? dhh_s : wsm_s,
            (t == 0) ? decB0 : decB, cbuf, hb[(t + 1) & 1],
            nullptr, nullptr, zw_s, z_b, out, t);

    z_final<<<zgrid, 256, 0, stream>>>(hb[0], zw_s, z_b, out);
}